// Round 5
// baseline (645.246 us; speedup 1.0000x reference)
//
#include <hip/hip_runtime.h>
#include <hip/hip_cooperative_groups.h>

namespace cg = cooperative_groups;

// All inputs and the output are float32 (established rounds 0-3).
// R4 profile: EVERY dispatch costs ~50-62us regardless of work (gemm24: 62us at
// 0.76% VALUBusy, 0.5% HBM) -> per-dispatch overhead dominates. This round: the
// whole pipeline is ONE cooperative kernel with grid.sync() between stages.

__device__ __forceinline__ float leaky(float v) { return v >= 0.f ? v : 0.2f * v; }

struct Params {
    const float *h, *rank_emb, *st_w1, *st_b1, *st_w2, *st_b2;
    const float *rm_w1, *rm_b1, *rm_w2, *rm_b2;
    const float *mx_w1, *mx_b1, *mx_w2, *mx_b2;
    const float *my_w1, *my_b1, *my_w2, *my_b2;
    const float *ax_w1, *ax_b1, *ax_w2, *ax_b2;
    const float *ay_w1, *ay_b1, *ay_w2, *ay_b2;
    const float *mult_w, *addx_w, *addy_w, *gbias;
    float *hid1, *shared_, *re_bias, *rfh, *rf, *hcat, *Pcat, *out;
};

union SMem {
    struct { float a[64][72]; float w[64][72]; } g;      // 64x64 gemm + N=24 gemm
    struct { float a[64][34]; float w[64][34]; } g32;    // 32x32 gemm
    struct { float re[256]; } pre;                       // prebias
    struct {
        float cp[48][25]; float sw[33];
        float u[16][132]; float v[16][132];
        float dx[128]; float dy[128];
    } d;                                                 // spline+depth
};

// ---------- 32x32-tile GEMM (L1, L2): out[b0..+32, n0..+32] over full K ----------
__device__ void gemm32_dev(SMem& sm, int tid, int b0, int n0,
                           const float* __restrict__ in, int K, int N,
                           const float* __restrict__ W, const float* __restrict__ bias,
                           float* __restrict__ out, bool lk)
{
    const int nq = tid & 15, bq = tid >> 4;
    float bv0 = bias[n0 + nq * 2], bv1 = bias[n0 + nq * 2 + 1];
    float a00 = bv0, a01 = bv1, a10 = bv0, a11 = bv1;
    for (int k0 = 0; k0 < K; k0 += 64) {
        #pragma unroll
        for (int j = 0; j < 8; ++j) {
            int idx = tid + j * 256;
            int k = idx & 63, c = idx >> 6;
            float v = in[(size_t)(b0 + c) * K + k0 + k];
            if (lk) v = leaky(v);
            sm.g32.a[k][c] = v;
            int n = idx & 31, k2 = idx >> 5;
            sm.g32.w[k2][n] = W[(size_t)(k0 + k2) * N + n0 + n];
        }
        __syncthreads();
        #pragma unroll 32
        for (int kk = 0; kk < 64; ++kk) {
            float2 a = *(const float2*)&sm.g32.a[kk][bq * 2];
            float2 w = *(const float2*)&sm.g32.w[kk][nq * 2];
            a00 += a.x * w.x; a01 += a.x * w.y;
            a10 += a.y * w.x; a11 += a.y * w.y;
        }
        __syncthreads();
    }
    out[(size_t)(b0 + bq * 2) * N + n0 + nq * 2]         = a00;
    out[(size_t)(b0 + bq * 2) * N + n0 + nq * 2 + 1]     = a01;
    out[(size_t)(b0 + bq * 2 + 1) * N + n0 + nq * 2]     = a10;
    out[(size_t)(b0 + bq * 2 + 1) * N + n0 + nq * 2 + 1] = a11;
}

// ---------- 64x64-tile rank GEMM (L3, L4, G2) ----------
__device__ void gemm64_dev(SMem& sm, int tid, int n0,
                           const float* __restrict__ inb, int in_bs,
                           const float* __restrict__ Wp, const float* __restrict__ bp,
                           float* __restrict__ ob, int out_bs,
                           int K, int N, bool lk)
{
    const int nq = tid & 15, bq = tid >> 4;
    float acc[4][4];
    #pragma unroll
    for (int j = 0; j < 4; ++j) {
        float bv = bp[n0 + nq * 4 + j];
        #pragma unroll
        for (int i = 0; i < 4; ++i) acc[i][j] = bv;
    }
    for (int k0 = 0; k0 < K; k0 += 64) {
        #pragma unroll
        for (int j = 0; j < 16; ++j) {
            int idx = tid + j * 256;
            int k = idx & 63, b = idx >> 6;
            float v = inb[(size_t)b * in_bs + k0 + k];
            if (lk) v = leaky(v);
            sm.g.a[k][b] = v;
        }
        #pragma unroll
        for (int j = 0; j < 16; ++j) {
            int idx = tid + j * 256;
            int n = idx & 63, k = idx >> 6;
            sm.g.w[k][n] = Wp[(size_t)(k0 + k) * N + n0 + n];
        }
        __syncthreads();
        #pragma unroll 16
        for (int kk = 0; kk < 64; ++kk) {
            float4 a = *(const float4*)&sm.g.a[kk][bq * 4];
            float4 w = *(const float4*)&sm.g.w[kk][nq * 4];
            float av[4] = {a.x, a.y, a.z, a.w};
            float wv[4] = {w.x, w.y, w.z, w.w};
            #pragma unroll
            for (int i = 0; i < 4; ++i)
                #pragma unroll
                for (int j = 0; j < 4; ++j)
                    acc[i][j] += av[i] * wv[j];
        }
        __syncthreads();
    }
    #pragma unroll
    for (int i = 0; i < 4; ++i) {
        float* op = ob + (size_t)(bq * 4 + i) * out_bs + n0 + nq * 4;
        float4 o; o.x = acc[i][0]; o.y = acc[i][1]; o.z = acc[i][2]; o.w = acc[i][3];
        *(float4*)op = o;
    }
}

// ---------- N=24 head output layer (G3), K=256, 256 thr = 8 nq x 32 bq, thread 2b x 4n ----------
__device__ void gemm24_dev(SMem& sm, int tid,
                           const float* __restrict__ inb, int in_bs,
                           const float* __restrict__ Wp, const float* __restrict__ bp,
                           float* __restrict__ ob)
{
    const int nq = tid & 7, bq = tid >> 3;
    float acc[2][4];
    #pragma unroll
    for (int j = 0; j < 4; ++j) {
        float bv = (nq < 6) ? bp[nq * 4 + j] : 0.f;
        acc[0][j] = bv; acc[1][j] = bv;
    }
    for (int k0 = 0; k0 < 256; k0 += 64) {
        #pragma unroll
        for (int j = 0; j < 16; ++j) {
            int idx = tid + j * 256;
            int k = idx & 63, b = idx >> 6;
            sm.g.a[k][b] = leaky(inb[(size_t)b * in_bs + k0 + k]);
        }
        #pragma unroll
        for (int j = 0; j < 8; ++j) {
            int idx = tid + j * 256;
            int n = idx & 31, k = idx >> 5;
            sm.g.w[k][n] = (n < 24) ? Wp[(size_t)(k0 + k) * 24 + n] : 0.f;
        }
        __syncthreads();
        #pragma unroll 16
        for (int kk = 0; kk < 64; ++kk) {
            float2 a = *(const float2*)&sm.g.a[kk][bq * 2];
            float4 w = *(const float4*)&sm.g.w[kk][nq * 4];
            acc[0][0] += a.x * w.x; acc[0][1] += a.x * w.y; acc[0][2] += a.x * w.z; acc[0][3] += a.x * w.w;
            acc[1][0] += a.y * w.x; acc[1][1] += a.y * w.y; acc[1][2] += a.y * w.z; acc[1][3] += a.y * w.w;
        }
        __syncthreads();
    }
    if (nq < 6) {
        #pragma unroll
        for (int i = 0; i < 2; ++i) {
            float* op = ob + (size_t)(bq * 2 + i) * 1152 + nq * 4;
            #pragma unroll
            for (int j = 0; j < 4; ++j) op[j] = acc[i][j];
        }
    }
}

// ---------- prebias: re_bias[r,h] = rm_b1[r,h] + sum_d rank_emb[r,d]*rm_w1[r,256+d,h] ----------
__device__ void prebias_dev(SMem& sm, int tid, int r, const Params& p) {
    sm.pre.re[tid] = p.rank_emb[r * 256 + tid];
    __syncthreads();
    float acc = p.rm_b1[r * 256 + tid];
    const float* w = p.rm_w1 + ((size_t)r * 512 + 256) * 256 + tid;
    #pragma unroll 8
    for (int d = 0; d < 256; ++d) acc += sm.pre.re[d] * w[(size_t)d * 256];
    p.re_bias[r * 256 + tid] = acc;
}

// ---------- spline helpers ----------
struct SCtx { float h00, h10, h01, h11; int seg, sm1, s1, sp2; };
__device__ __forceinline__ SCtx make_spline(int gpos) {
    const float eps = 0.001f;
    float t = eps + (float)gpos * ((1.f - 2.f * eps) / 511.f);
    float ts = t * 23.f;
    int seg = (int)ts; if (seg > 22) seg = 22;
    float tau = ts - (float)seg;
    tau = fminf(fmaxf(tau, 0.f), 0.9999f);
    float t2 = tau * tau, t3 = t2 * tau;
    SCtx c;
    c.h00 = 2.f * t3 - 3.f * t2 + 1.f;
    c.h10 = t3 - 2.f * t2 + tau;
    c.h01 = -2.f * t3 + 3.f * t2;
    c.h11 = t3 - t2;
    c.seg = seg; c.sm1 = seg > 0 ? seg - 1 : 0; c.s1 = seg + 1;
    c.sp2 = (seg + 2 < 24) ? seg + 2 : 23;
    return c;
}
__device__ __forceinline__ float spl_eval(const SMem& sm, const SCtx& c, int row) {
    const float msc = 0.5f / 23.f;
    float pk = sm.d.cp[row][c.seg], pk1 = sm.d.cp[row][c.s1];
    float mk  = msc * (pk1 - sm.d.cp[row][c.sm1]);
    float mk1 = msc * (sm.d.cp[row][c.sp2] - pk);
    return c.h00 * pk + c.h10 * mk + c.h01 * pk1 + c.h11 * mk1;
}

// ---------- fused spline + depth; block handles (b = blk>>2, h0 = (blk&3)*128), 4 w-tiles ----------
__device__ void depth_dev(SMem& sm, int tid, int blk, const Params& p) {
    const int b = blk >> 2;
    const int h0 = (blk & 3) * 128;
    for (int idx = tid; idx < 1152; idx += 256)
        sm.d.cp[idx / 24][idx % 24] = p.Pcat[(size_t)b * 1152 + idx];
    if (tid == 0) {
        float e[16], m, s;
        m = -1e30f; for (int i = 0; i < 16; ++i) m = fmaxf(m, p.mult_w[i]);
        s = 0.f;    for (int i = 0; i < 16; ++i) { e[i] = __expf(p.mult_w[i] - m); s += e[i]; }
        for (int i = 0; i < 16; ++i) sm.d.sw[i] = e[i] / s;
        m = -1e30f; for (int i = 0; i < 8; ++i) m = fmaxf(m, p.addx_w[i]);
        s = 0.f;    for (int i = 0; i < 8; ++i) { e[i] = __expf(p.addx_w[i] - m); s += e[i]; }
        for (int i = 0; i < 8; ++i) sm.d.sw[16 + i] = e[i] / s;
        m = -1e30f; for (int i = 0; i < 8; ++i) m = fmaxf(m, p.addy_w[i]);
        s = 0.f;    for (int i = 0; i < 8; ++i) { e[i] = __expf(p.addy_w[i] - m); s += e[i]; }
        for (int i = 0; i < 8; ++i) sm.d.sw[24 + i] = e[i] / s;
        sm.d.sw[32] = p.gbias[0];
    }
    __syncthreads();
    if (tid < 128) {     // v / dy for the fixed h-tile (once)
        SCtx c = make_spline(h0 + tid);
        #pragma unroll
        for (int r = 0; r < 16; ++r) sm.d.v[r][tid] = spl_eval(sm, c, 16 + r);
        float dy = 0.f;
        #pragma unroll
        for (int r = 0; r < 8; ++r) dy += sm.d.sw[24 + r] * spl_eval(sm, c, 40 + r);
        sm.d.dy[tid] = dy;
    }
    const int tw = tid & 15, th = tid >> 4;
    for (int i = 0; i < 4; ++i) {
        const int w0 = i * 128;
        if (tid < 128) {  // u / dx for this w-tile
            SCtx c = make_spline(w0 + tid);
            #pragma unroll
            for (int r = 0; r < 16; ++r) sm.d.u[r][tid] = sm.d.sw[r] * spl_eval(sm, c, r);
            float dx = sm.d.sw[32];
            #pragma unroll
            for (int r = 0; r < 8; ++r) dx += sm.d.sw[16 + r] * spl_eval(sm, c, 32 + r);
            sm.d.dx[tid] = dx;
        }
        __syncthreads();
        float acc[8][8];
        #pragma unroll
        for (int a = 0; a < 8; ++a)
            #pragma unroll
            for (int j = 0; j < 8; ++j) acc[a][j] = 0.f;
        #pragma unroll
        for (int r = 0; r < 16; ++r) {
            float4 va0 = *(const float4*)&sm.d.v[r][th * 8];
            float4 va1 = *(const float4*)&sm.d.v[r][th * 8 + 4];
            float4 ub0 = *(const float4*)&sm.d.u[r][tw * 8];
            float4 ub1 = *(const float4*)&sm.d.u[r][tw * 8 + 4];
            float va[8] = {va0.x, va0.y, va0.z, va0.w, va1.x, va1.y, va1.z, va1.w};
            float ub[8] = {ub0.x, ub0.y, ub0.z, ub0.w, ub1.x, ub1.y, ub1.z, ub1.w};
            #pragma unroll
            for (int a = 0; a < 8; ++a)
                #pragma unroll
                for (int j = 0; j < 8; ++j)
                    acc[a][j] += va[a] * ub[j];
        }
        #pragma unroll
        for (int a = 0; a < 8; ++a) {
            float dyh = sm.d.dy[th * 8 + a];
            float* op = p.out + (size_t)b * 262144 + (size_t)(h0 + th * 8 + a) * 512 + w0 + tw * 8;
            float4 o0, o1;
            o0.x = acc[a][0] + sm.d.dx[tw * 8 + 0] + dyh;
            o0.y = acc[a][1] + sm.d.dx[tw * 8 + 1] + dyh;
            o0.z = acc[a][2] + sm.d.dx[tw * 8 + 2] + dyh;
            o0.w = acc[a][3] + sm.d.dx[tw * 8 + 3] + dyh;
            o1.x = acc[a][4] + sm.d.dx[tw * 8 + 4] + dyh;
            o1.y = acc[a][5] + sm.d.dx[tw * 8 + 5] + dyh;
            o1.z = acc[a][6] + sm.d.dx[tw * 8 + 6] + dyh;
            o1.w = acc[a][7] + sm.d.dx[tw * 8 + 7] + dyh;
            *(float4*)op = o0;
            *(float4*)(op + 4) = o1;
        }
        __syncthreads();
    }
}

// ---------- the single fused kernel ----------
__global__ __launch_bounds__(256, 2) void fused_kernel(Params p) {
    __shared__ SMem sm;
    cg::grid_group grid = cg::this_grid();
    const int tid = threadIdx.x;
    const int blk = blockIdx.x;

    // S0: L1 (h @ st_w1 + st_b1 -> hid1, K=768, N=512; 32 tiles)  ||  prebias (24 blocks)
    if (blk < 32) {
        gemm32_dev(sm, tid, (blk & 1) * 32, (blk >> 1) * 32, p.h, 768, 512, p.st_w1, p.st_b1, p.hid1, false);
    } else if (blk < 56) {
        prebias_dev(sm, tid, blk - 32, p);
    }
    __threadfence(); grid.sync();

    // S1: L2 (leaky(hid1) @ st_w2 + st_b2 -> shared_, K=512, N=256; 16 tiles)
    if (blk < 16) {
        gemm32_dev(sm, tid, (blk & 1) * 32, (blk >> 1) * 32, p.hid1, 512, 256, p.st_w2, p.st_b2, p.shared_, true);
    }
    __threadfence(); grid.sync();

    // S2: L3 (shared_ @ rm_w1[:, :256, :] + re_bias -> rfh; 24 ranks x 4 n-tiles)
    if (blk < 96) {
        int x = blk & 3, y = blk >> 2;
        gemm64_dev(sm, tid, x * 64, p.shared_, 256,
                   p.rm_w1 + (size_t)y * 512 * 256, p.re_bias + y * 256,
                   p.rfh + y * 256, 6144, 256, 256, false);
    }
    __threadfence(); grid.sync();

    // S3: L4 (leaky(rfh) @ rm_w2 + rm_b2 -> rf)
    if (blk < 96) {
        int x = blk & 3, y = blk >> 2;
        gemm64_dev(sm, tid, x * 64, p.rfh + y * 256, 6144,
                   p.rm_w2 + (size_t)y * 65536, p.rm_b2 + y * 256,
                   p.rf + y * 256, 6144, 256, 256, true);
    }
    __threadfence(); grid.sync();

    // S4: G2 (rf -> hcat, 48 head-rank rows x 4 n-tiles)
    if (blk < 192) {
        int x = blk & 3, y = blk >> 2;
        const float *W1, *B1; int r_in;
        if (y < 16)      {            W1 = p.mx_w1 + (size_t)y  * 65536; B1 = p.mx_b1 + y  * 256; r_in = y; }
        else if (y < 32) { int rw = y - 16; W1 = p.my_w1 + (size_t)rw * 65536; B1 = p.my_b1 + rw * 256; r_in = rw; }
        else if (y < 40) { int rw = y - 32; W1 = p.ax_w1 + (size_t)rw * 65536; B1 = p.ax_b1 + rw * 256; r_in = 16 + rw; }
        else             { int rw = y - 40; W1 = p.ay_w1 + (size_t)rw * 65536; B1 = p.ay_b1 + rw * 256; r_in = 16 + rw; }
        gemm64_dev(sm, tid, x * 64, p.rf + r_in * 256, 6144, W1, B1,
                   p.hcat + y * 256, 12288, 256, 256, false);
    }
    __threadfence(); grid.sync();

    // S5: G3 (leaky(hcat) -> Pcat, 48 rows, N=24)
    if (blk < 48) {
        int y = blk;
        const float *W2, *B2;
        if (y < 16)      {            W2 = p.mx_w2 + (size_t)y  * 6144; B2 = p.mx_b2 + y  * 24; }
        else if (y < 32) { int rw = y - 16; W2 = p.my_w2 + (size_t)rw * 6144; B2 = p.my_b2 + rw * 24; }
        else if (y < 40) { int rw = y - 32; W2 = p.ax_w2 + (size_t)rw * 6144; B2 = p.ax_b2 + rw * 24; }
        else             { int rw = y - 40; W2 = p.ay_w2 + (size_t)rw * 6144; B2 = p.ay_b2 + rw * 24; }
        gemm24_dev(sm, tid, p.hcat + y * 256, 12288, W2, B2, p.Pcat + y * 24);
    }
    __threadfence(); grid.sync();

    // S6: fused spline + depth (all 256 blocks)
    depth_dev(sm, tid, blk, p);
}

// ---------- host ----------
extern "C" void kernel_launch(void* const* d_in, const int* in_sizes, int n_in,
                              void* d_out, int out_size, void* d_ws, size_t ws_size,
                              hipStream_t stream) {
    (void)in_sizes; (void)n_in; (void)out_size; (void)ws_size;
    float* ws = (float*)d_ws;

    Params p;
    p.h        = (const float*)d_in[0];
    p.rank_emb = (const float*)d_in[1];
    p.st_w1    = (const float*)d_in[2];
    p.st_b1    = (const float*)d_in[3];
    p.st_w2    = (const float*)d_in[4];
    p.st_b2    = (const float*)d_in[5];
    p.rm_w1    = (const float*)d_in[6];
    p.rm_b1    = (const float*)d_in[7];
    p.rm_w2    = (const float*)d_in[8];
    p.rm_b2    = (const float*)d_in[9];
    p.mx_w1    = (const float*)d_in[10];
    p.mx_b1    = (const float*)d_in[11];
    p.mx_w2    = (const float*)d_in[12];
    p.mx_b2    = (const float*)d_in[13];
    p.my_w1    = (const float*)d_in[14];
    p.my_b1    = (const float*)d_in[15];
    p.my_w2    = (const float*)d_in[16];
    p.my_b2    = (const float*)d_in[17];
    p.ax_w1    = (const float*)d_in[18];
    p.ax_b1    = (const float*)d_in[19];
    p.ax_w2    = (const float*)d_in[20];
    p.ax_b2    = (const float*)d_in[21];
    p.ay_w1    = (const float*)d_in[22];
    p.ay_b1    = (const float*)d_in[23];
    p.ay_w2    = (const float*)d_in[24];
    p.ay_b2    = (const float*)d_in[25];
    p.mult_w   = (const float*)d_in[26];
    p.addx_w   = (const float*)d_in[27];
    p.addy_w   = (const float*)d_in[28];
    p.gbias    = (const float*)d_in[29];
    p.hid1     = ws;                 // 64x512
    p.shared_  = ws + 32768;         // 64x256
    p.re_bias  = ws + 49152;         // 24x256
    p.rfh      = ws + 55296;         // 64x24x256
    p.rf       = ws + 448512;        // 64x24x256
    p.hcat     = ws + 841728;        // 64x48x256
    p.Pcat     = ws + 1628160;       // 64x48x24
    p.out      = (float*)d_out;

    void* args[] = { &p };
    hipLaunchCooperativeKernel((const void*)fused_kernel, dim3(256), dim3(256), args, 0, stream);
}

// Round 6
// 312.919 us; speedup vs baseline: 2.0620x; 2.0620x over previous
//
#include <hip/hip_runtime.h>

// All inputs and the output are float32 (established rounds 0-3).
// R5: cooperative mega-kernel REGRESSED (480us kernel; grid.sync + 1 blk/CU serial
// phases). R3/R4/R5 comparison shows achieved BW scales with block count ->
// latency-bound regime. This round: R3-style wide split-K grids WITHOUT atomics:
// each split-K partial goes to its own buffer; the consumer sums partials while
// staging (inputs are re-read there anyway).

__device__ __forceinline__ float leaky(float v) { return v >= 0.f ? v : 0.2f * v; }

struct GemmArgs {
    const float* W[4];
    const float* bias[4];
    int gstart[5];
    int in_roff[4];
    int rmul[4];
    int wstride[4];
};

// ---------- 32x32-tile split-K GEMM (L1, L2). Single k-round-trip per block.
// out partial z: outp[z*ops + b*N + n] = (z==0 ? bias : 0) + sum_{k in slice z} ...
// A input may itself be PIN partials (summed at staging, then optional leaky).
// PRE: blocks x>=nblk (z==0) compute re_bias instead (fused prebias).
template<int SLICE, int PIN, bool LK, bool PRE>
__global__ __launch_bounds__(256, 2) void gemm32s_kernel(
    const float* __restrict__ inp, long ips, int K, int N, int nblk,
    const float* __restrict__ W, const float* __restrict__ bias,
    float* __restrict__ outp, long ops,
    const float* __restrict__ rank_emb, const float* __restrict__ rm_w1,
    const float* __restrict__ rm_b1, float* __restrict__ re_bias)
{
    __shared__ __align__(16) float a_lds[SLICE][34];
    __shared__ __align__(16) float w_lds[SLICE][34];
    __shared__ float re[256];
    const int tid = threadIdx.x;
    const int x = blockIdx.x, z = blockIdx.z;
    if (PRE && x >= nblk) {
        if (z != 0) return;
        const int r = x - nblk;
        re[tid] = rank_emb[r * 256 + tid];
        __syncthreads();
        float acc = rm_b1[r * 256 + tid];
        const float* w = rm_w1 + ((size_t)r * 512 + 256) * 256 + tid;
        #pragma unroll 8
        for (int d = 0; d < 256; ++d) acc += re[d] * w[(size_t)d * 256];
        re_bias[r * 256 + tid] = acc;
        return;
    }
    const int b0 = (x & 1) * 32, n0 = (x >> 1) * 32;
    const int nq = tid & 15, bq = tid >> 4;
    const int k0 = z * SLICE;
    float a00, a01, a10, a11;
    if (z == 0) {
        float bv0 = bias[n0 + nq * 2], bv1 = bias[n0 + nq * 2 + 1];
        a00 = bv0; a01 = bv1; a10 = bv0; a11 = bv1;
    } else { a00 = a01 = a10 = a11 = 0.f; }
    // stage A (SLICE k x 32 b), k fastest (coalesced), sum PIN partials
    #pragma unroll
    for (int j = 0; j < SLICE * 32 / 256; ++j) {
        int idx = tid + j * 256;
        int k = idx & (SLICE - 1), c = idx / SLICE;
        float v = 0.f;
        #pragma unroll
        for (int p = 0; p < PIN; ++p) v += inp[(size_t)p * ips + (size_t)(b0 + c) * K + k0 + k];
        if (LK) v = leaky(v);
        a_lds[k][c] = v;
    }
    // stage W (SLICE k x 32 n), n fastest
    #pragma unroll
    for (int j = 0; j < SLICE * 32 / 256; ++j) {
        int idx = tid + j * 256;
        int n = idx & 31, kk = idx >> 5;
        w_lds[kk][n] = W[(size_t)(k0 + kk) * N + n0 + n];
    }
    __syncthreads();
    #pragma unroll 32
    for (int kk = 0; kk < SLICE; ++kk) {
        float2 a = *(const float2*)&a_lds[kk][bq * 2];
        float2 w = *(const float2*)&w_lds[kk][nq * 2];
        a00 += a.x * w.x; a01 += a.x * w.y;
        a10 += a.y * w.x; a11 += a.y * w.y;
    }
    float* ob = outp + (size_t)z * ops;
    ob[(size_t)(b0 + bq * 2) * N + n0 + nq * 2]         = a00;
    ob[(size_t)(b0 + bq * 2) * N + n0 + nq * 2 + 1]     = a01;
    ob[(size_t)(b0 + bq * 2 + 1) * N + n0 + nq * 2]     = a10;
    ob[(size_t)(b0 + bq * 2 + 1) * N + n0 + nq * 2 + 1] = a11;
}

// ---------- 64x64-tile batched-rank split-K GEMM (L3, L4, G2). K=256, N=256.
// z in {0,1}: covers k in [z*128, z*128+128) as two 64-steps. Input = PIN partials.
template<int PIN, bool LK>
__global__ __launch_bounds__(256, 2) void gemm64s_kernel(
    const float* __restrict__ inp, long ips, int in_bs,
    float* __restrict__ outp, long ops, int out_bs, GemmArgs ga)
{
    __shared__ __align__(16) float a_lds[64][72];
    __shared__ __align__(16) float w_lds[64][72];
    const int tid = threadIdx.x;
    const int nq = tid & 15, bq = tid >> 4;
    const int n0 = blockIdx.x * 64;
    const int y = blockIdx.y, z = blockIdx.z;
    int g = 0;
    while (g < 3 && y >= ga.gstart[g + 1]) ++g;
    const int rw = y - ga.gstart[g];
    const int r_in = ga.in_roff[g] + rw * ga.rmul[g];
    const float* Wp = ga.W[g] + (size_t)rw * ga.wstride[g];
    const size_t in_base = (size_t)r_in * 256;

    float acc[4][4];
    #pragma unroll
    for (int j = 0; j < 4; ++j) {
        float bv = (z == 0) ? ga.bias[g][(size_t)rw * 256 + n0 + nq * 4 + j] : 0.f;
        #pragma unroll
        for (int i = 0; i < 4; ++i) acc[i][j] = bv;
    }
    for (int k0 = z * 128; k0 < z * 128 + 128; k0 += 64) {
        #pragma unroll
        for (int j = 0; j < 16; ++j) {
            int idx = tid + j * 256;
            int k = idx & 63, b = idx >> 6;
            float v = 0.f;
            #pragma unroll
            for (int p = 0; p < PIN; ++p)
                v += inp[(size_t)p * ips + (size_t)b * in_bs + in_base + k0 + k];
            if (LK) v = leaky(v);
            a_lds[k][b] = v;
        }
        #pragma unroll
        for (int j = 0; j < 16; ++j) {
            int idx = tid + j * 256;
            int n = idx & 63, k = idx >> 6;
            w_lds[k][n] = Wp[(size_t)(k0 + k) * 256 + n0 + n];
        }
        __syncthreads();
        #pragma unroll 16
        for (int kk = 0; kk < 64; ++kk) {
            float4 a = *(const float4*)&a_lds[kk][bq * 4];
            float4 w = *(const float4*)&w_lds[kk][nq * 4];
            float av[4] = {a.x, a.y, a.z, a.w};
            float wv[4] = {w.x, w.y, w.z, w.w};
            #pragma unroll
            for (int i = 0; i < 4; ++i)
                #pragma unroll
                for (int j = 0; j < 4; ++j)
                    acc[i][j] += av[i] * wv[j];
        }
        __syncthreads();
    }
    #pragma unroll
    for (int i = 0; i < 4; ++i) {
        float* op = outp + (size_t)z * ops + (size_t)(bq * 4 + i) * out_bs + (size_t)y * 256 + n0 + nq * 4;
        float4 o; o.x = acc[i][0]; o.y = acc[i][1]; o.z = acc[i][2]; o.w = acc[i][3];
        *(float4*)op = o;
    }
}

// ---------- N=24 head output layer (G3), K=256 split over z in {0..3} (slice 64).
// Input = 2 hcat partials (summed + leaky). 128 thr = 8 nq x 16 bq, thread 4b x 4n.
__global__ __launch_bounds__(128, 2) void gemm24s_kernel(
    const float* __restrict__ inp, long ips,
    float* __restrict__ outp, long ops, GemmArgs ga)
{
    __shared__ __align__(16) float a_lds[64][72];
    __shared__ __align__(16) float w_lds[64][36];
    const int tid = threadIdx.x;
    const int nq = tid & 7, bq = tid >> 3;   // nq<6 valid (24 cols)
    const int y = blockIdx.y, z = blockIdx.z;
    int g = 0;
    while (g < 3 && y >= ga.gstart[g + 1]) ++g;
    const int rw = y - ga.gstart[g];
    const float* Wp = ga.W[g] + (size_t)rw * ga.wstride[g];
    const int k0 = z * 64;

    float acc[4][4];
    #pragma unroll
    for (int j = 0; j < 4; ++j) {
        float bv = (z == 0 && nq < 6) ? ga.bias[g][(size_t)rw * 24 + nq * 4 + j] : 0.f;
        #pragma unroll
        for (int i = 0; i < 4; ++i) acc[i][j] = bv;
    }
    #pragma unroll
    for (int j = 0; j < 32; ++j) {
        int idx = tid + j * 128;
        int k = idx & 63, b = idx >> 6;
        float v = inp[(size_t)b * 12288 + (size_t)y * 256 + k0 + k]
                + inp[ips + (size_t)b * 12288 + (size_t)y * 256 + k0 + k];
        a_lds[k][b] = leaky(v);
    }
    #pragma unroll
    for (int j = 0; j < 16; ++j) {
        int idx = tid + j * 128;
        int n = idx & 31, k = idx >> 5;
        w_lds[k][n] = (n < 24) ? Wp[(size_t)(k0 + k) * 24 + n] : 0.f;
    }
    __syncthreads();
    #pragma unroll 16
    for (int kk = 0; kk < 64; ++kk) {
        float4 a = *(const float4*)&a_lds[kk][bq * 4];
        float4 w = *(const float4*)&w_lds[kk][nq * 4];
        float av[4] = {a.x, a.y, a.z, a.w};
        float wv[4] = {w.x, w.y, w.z, w.w};
        #pragma unroll
        for (int i = 0; i < 4; ++i)
            #pragma unroll
            for (int j = 0; j < 4; ++j)
                acc[i][j] += av[i] * wv[j];
    }
    if (nq < 6) {
        #pragma unroll
        for (int i = 0; i < 4; ++i) {
            float* op = outp + (size_t)z * ops + (size_t)(bq * 4 + i) * 1152 + y * 24 + nq * 4;
            #pragma unroll
            for (int j = 0; j < 4; ++j) op[j] = acc[i][j];
        }
    }
}

// ---------- fused spline + depth; sums 4 Pcat partials at cp-load.
// Pcat rows: [Px_m 0..15, Py_m 16..31, Px_a 32..39, Py_a 40..47]
__global__ __launch_bounds__(256, 2) void depth_fused_kernel(
    const float* __restrict__ Pcatp, long ips,
    const float* __restrict__ mult_w, const float* __restrict__ addx_w,
    const float* __restrict__ addy_w, const float* __restrict__ gbias,
    float* __restrict__ out)
{
    __shared__ float cp[48][25];
    __shared__ float sw[33];
    __shared__ __align__(16) float u_s[16][132];
    __shared__ __align__(16) float v_s[16][132];
    __shared__ float dx_s[128], dy_s[128];
    const int tid = threadIdx.x;
    const int b = blockIdx.z, h0 = blockIdx.y * 128, w0 = blockIdx.x * 128;
    for (int idx = tid; idx < 1152; idx += 256) {
        float v = Pcatp[(size_t)b * 1152 + idx]
                + Pcatp[ips + (size_t)b * 1152 + idx]
                + Pcatp[2 * ips + (size_t)b * 1152 + idx]
                + Pcatp[3 * ips + (size_t)b * 1152 + idx];
        cp[idx / 24][idx % 24] = v;
    }
    if (tid == 0) {
        float e[16], m, s;
        m = -1e30f; for (int i = 0; i < 16; ++i) m = fmaxf(m, mult_w[i]);
        s = 0.f;    for (int i = 0; i < 16; ++i) { e[i] = __expf(mult_w[i] - m); s += e[i]; }
        for (int i = 0; i < 16; ++i) sw[i] = e[i] / s;
        m = -1e30f; for (int i = 0; i < 8; ++i) m = fmaxf(m, addx_w[i]);
        s = 0.f;    for (int i = 0; i < 8; ++i) { e[i] = __expf(addx_w[i] - m); s += e[i]; }
        for (int i = 0; i < 8; ++i) sw[16 + i] = e[i] / s;
        m = -1e30f; for (int i = 0; i < 8; ++i) m = fmaxf(m, addy_w[i]);
        s = 0.f;    for (int i = 0; i < 8; ++i) { e[i] = __expf(addy_w[i] - m); s += e[i]; }
        for (int i = 0; i < 8; ++i) sw[24 + i] = e[i] / s;
        sw[32] = gbias[0];
    }
    __syncthreads();
    {   // spline: tid<128 -> w positions; tid>=128 -> h positions
        const int local = tid & 127;
        const int gpos = (tid < 128 ? w0 : h0) + local;
        const float eps = 0.001f;
        float t = eps + (float)gpos * ((1.f - 2.f * eps) / 511.f);
        float ts = t * 23.f;
        int seg = (int)ts; if (seg > 22) seg = 22;
        float tau = ts - (float)seg;
        tau = fminf(fmaxf(tau, 0.f), 0.9999f);
        float t2 = tau * tau, t3 = t2 * tau;
        float h00 = 2.f * t3 - 3.f * t2 + 1.f;
        float h10 = t3 - 2.f * t2 + tau;
        float h01 = -2.f * t3 + 3.f * t2;
        float h11 = t3 - t2;
        int sm1 = seg > 0 ? seg - 1 : 0;
        int s1 = seg + 1;
        int sp2 = s1 < 23 ? s1 + 1 : 23;
        const float msc = 0.5f / 23.f;
        auto spl = [&](int row) -> float {
            float pk = cp[row][seg], pk1 = cp[row][s1];
            float mk  = msc * (pk1 - cp[row][sm1]);
            float mk1 = msc * (cp[row][sp2] - pk);
            return h00 * pk + h10 * mk + h01 * pk1 + h11 * mk1;
        };
        if (tid < 128) {
            #pragma unroll
            for (int r = 0; r < 16; ++r) u_s[r][local] = sw[r] * spl(r);
            float dx = sw[32];
            #pragma unroll
            for (int r = 0; r < 8; ++r) dx += sw[16 + r] * spl(32 + r);
            dx_s[local] = dx;
        } else {
            #pragma unroll
            for (int r = 0; r < 16; ++r) v_s[r][local] = spl(16 + r);
            float dy = 0.f;
            #pragma unroll
            for (int r = 0; r < 8; ++r) dy += sw[24 + r] * spl(40 + r);
            dy_s[local] = dy;
        }
    }
    __syncthreads();
    const int tw = tid & 15, th = tid >> 4;
    float acc[8][8];
    #pragma unroll
    for (int i = 0; i < 8; ++i)
        #pragma unroll
        for (int j = 0; j < 8; ++j) acc[i][j] = 0.f;
    #pragma unroll
    for (int r = 0; r < 16; ++r) {
        float4 va0 = *(const float4*)&v_s[r][th * 8];
        float4 va1 = *(const float4*)&v_s[r][th * 8 + 4];
        float4 ub0 = *(const float4*)&u_s[r][tw * 8];
        float4 ub1 = *(const float4*)&u_s[r][tw * 8 + 4];
        float va[8] = {va0.x, va0.y, va0.z, va0.w, va1.x, va1.y, va1.z, va1.w};
        float ub[8] = {ub0.x, ub0.y, ub0.z, ub0.w, ub1.x, ub1.y, ub1.z, ub1.w};
        #pragma unroll
        for (int i = 0; i < 8; ++i)
            #pragma unroll
            for (int j = 0; j < 8; ++j)
                acc[i][j] += va[i] * ub[j];
    }
    #pragma unroll
    for (int i = 0; i < 8; ++i) {
        float dyh = dy_s[th * 8 + i];
        float* op = out + (size_t)b * 262144 + (size_t)(h0 + th * 8 + i) * 512 + w0 + tw * 8;
        float4 o0, o1;
        o0.x = acc[i][0] + dx_s[tw * 8 + 0] + dyh;
        o0.y = acc[i][1] + dx_s[tw * 8 + 1] + dyh;
        o0.z = acc[i][2] + dx_s[tw * 8 + 2] + dyh;
        o0.w = acc[i][3] + dx_s[tw * 8 + 3] + dyh;
        o1.x = acc[i][4] + dx_s[tw * 8 + 4] + dyh;
        o1.y = acc[i][5] + dx_s[tw * 8 + 5] + dyh;
        o1.z = acc[i][6] + dx_s[tw * 8 + 6] + dyh;
        o1.w = acc[i][7] + dx_s[tw * 8 + 7] + dyh;
        *(float4*)op = o0;
        *(float4*)(op + 4) = o1;
    }
}

// ---------- host ----------
extern "C" void kernel_launch(void* const* d_in, const int* in_sizes, int n_in,
                              void* d_out, int out_size, void* d_ws, size_t ws_size,
                              hipStream_t stream) {
    const float* in_h     = (const float*)d_in[0];
    const float* rank_emb = (const float*)d_in[1];
    const float* st_w1    = (const float*)d_in[2];
    const float* st_b1    = (const float*)d_in[3];
    const float* st_w2    = (const float*)d_in[4];
    const float* st_b2    = (const float*)d_in[5];
    const float* rm_w1    = (const float*)d_in[6];
    const float* rm_b1    = (const float*)d_in[7];
    const float* rm_w2    = (const float*)d_in[8];
    const float* rm_b2    = (const float*)d_in[9];
    const float* mx_w1    = (const float*)d_in[10];
    const float* mx_b1    = (const float*)d_in[11];
    const float* mx_w2    = (const float*)d_in[12];
    const float* mx_b2    = (const float*)d_in[13];
    const float* my_w1    = (const float*)d_in[14];
    const float* my_b1    = (const float*)d_in[15];
    const float* my_w2    = (const float*)d_in[16];
    const float* my_b2    = (const float*)d_in[17];
    const float* ax_w1    = (const float*)d_in[18];
    const float* ax_b1    = (const float*)d_in[19];
    const float* ax_w2    = (const float*)d_in[20];
    const float* ax_b2    = (const float*)d_in[21];
    const float* ay_w1    = (const float*)d_in[22];
    const float* ay_b1    = (const float*)d_in[23];
    const float* ay_w2    = (const float*)d_in[24];
    const float* ay_b2    = (const float*)d_in[25];
    const float* mult_w   = (const float*)d_in[26];
    const float* addx_w   = (const float*)d_in[27];
    const float* addy_w   = (const float*)d_in[28];
    const float* gbias    = (const float*)d_in[29];
    (void)in_sizes; (void)n_in; (void)out_size; (void)ws_size;

    float* ws = (float*)d_ws;
    float* hid1p  = ws;                      // 6 x (64x512)   = 196608
    float* shp    = ws + 196608;             // 8 x (64x256)   = 131072
    float* re_bias= ws + 327680;             // 24x256         = 6144
    float* rfhp   = ws + 333824;             // 2 x (64x24x256)= 786432
    float* rfp    = ws + 1120256;            // 2 x (64x24x256)= 786432
    float* hcatp  = ws + 1906688;            // 2 x (64x48x256)= 1572864
    float* Pcatp  = ws + 3479552;            // 4 x (64x48x24) = 294912

    const int BIG = 1 << 30;

    // D0: L1 split-K6 (slice 128): h @ st_w1 -> hid1p[6]; + fused prebias (24 blocks at x>=32)
    gemm32s_kernel<128, 1, false, true><<<dim3(56, 1, 6), 256, 0, stream>>>(
        in_h, 0, 768, 512, 32, st_w1, st_b1, hid1p, 32768,
        rank_emb, rm_w1, rm_b1, re_bias);

    // D1: L2 split-K8 (slice 64): leaky(sum hid1p) @ st_w2 -> shp[8]
    gemm32s_kernel<64, 6, true, false><<<dim3(16, 1, 8), 256, 0, stream>>>(
        hid1p, 32768, 512, 256, 16, st_w2, st_b2, shp, 16384,
        nullptr, nullptr, nullptr, nullptr);

    {   // D2: L3 split-K2: (sum shp) @ rm_w1[:, :256, :] + re_bias -> rfhp[2]
        GemmArgs a{}; a.W[0] = rm_w1; a.bias[0] = re_bias;
        a.gstart[0] = 0; a.gstart[1] = BIG; a.gstart[2] = BIG; a.gstart[3] = BIG; a.gstart[4] = BIG;
        a.in_roff[0] = 0; a.rmul[0] = 0; a.wstride[0] = 512 * 256;
        gemm64s_kernel<8, false><<<dim3(4, 24, 2), 256, 0, stream>>>(
            shp, 16384, 256, rfhp, 393216, 6144, a);
    }
    {   // D3: L4 split-K2: leaky(sum rfhp) @ rm_w2 + rm_b2 -> rfp[2]
        GemmArgs a{}; a.W[0] = rm_w2; a.bias[0] = rm_b2;
        a.gstart[0] = 0; a.gstart[1] = BIG; a.gstart[2] = BIG; a.gstart[3] = BIG; a.gstart[4] = BIG;
        a.in_roff[0] = 0; a.rmul[0] = 1; a.wstride[0] = 256 * 256;
        gemm64s_kernel<2, true><<<dim3(4, 24, 2), 256, 0, stream>>>(
            rfhp, 393216, 6144, rfp, 393216, 6144, a);
    }
    {   // D4: G2 split-K2: (sum rfp) -> hcatp[2] (48 head-rank rows)
        GemmArgs a{};
        a.W[0] = mx_w1; a.W[1] = my_w1; a.W[2] = ax_w1; a.W[3] = ay_w1;
        a.bias[0] = mx_b1; a.bias[1] = my_b1; a.bias[2] = ax_b1; a.bias[3] = ay_b1;
        a.gstart[0] = 0; a.gstart[1] = 16; a.gstart[2] = 32; a.gstart[3] = 40; a.gstart[4] = 48;
        a.in_roff[0] = 0; a.in_roff[1] = 0; a.in_roff[2] = 16; a.in_roff[3] = 16;
        a.rmul[0] = 1; a.rmul[1] = 1; a.rmul[2] = 1; a.rmul[3] = 1;
        a.wstride[0] = 65536; a.wstride[1] = 65536; a.wstride[2] = 65536; a.wstride[3] = 65536;
        gemm64s_kernel<2, false><<<dim3(4, 48, 2), 256, 0, stream>>>(
            rfp, 393216, 6144, hcatp, 786432, 12288, a);
    }
    {   // D5: G3 split-K4: leaky(sum hcatp) -> Pcatp[4] (B,48,24)
        GemmArgs a{};
        a.W[0] = mx_w2; a.W[1] = my_w2; a.W[2] = ax_w2; a.W[3] = ay_w2;
        a.bias[0] = mx_b2; a.bias[1] = my_b2; a.bias[2] = ax_b2; a.bias[3] = ay_b2;
        a.gstart[0] = 0; a.gstart[1] = 16; a.gstart[2] = 32; a.gstart[3] = 40; a.gstart[4] = 48;
        a.in_roff[0] = 0; a.in_roff[1] = 16; a.in_roff[2] = 32; a.in_roff[3] = 40;
        a.rmul[0] = 1; a.rmul[1] = 1; a.rmul[2] = 1; a.rmul[3] = 1;
        a.wstride[0] = 6144; a.wstride[1] = 6144; a.wstride[2] = 6144; a.wstride[3] = 6144;
        gemm24s_kernel<<<dim3(1, 48, 4), 128, 0, stream>>>(
            hcatp, 786432, Pcatp, 73728, a);
    }
    // D6: fused spline + depth (sums 4 Pcat partials)
    depth_fused_kernel<<<dim3(4, 4, 64), 256, 0, stream>>>(
        Pcatp, 73728, mult_w, addx_w, addy_w, gbias, (float*)d_out);
}